// Round 3
// baseline (232.930 us; speedup 1.0000x reference)
//
#include <hip/hip_runtime.h>

// StrokeField R9: register-broadcast blend loop (zero LDS in inner loop) +
// deterministic quarter-placement sort (no global cell atomics/scan).
// R8 post-mortem: kF VALUBusy fell 56->43% -- inner loop had a 2-deep
// dependent LDS chain (lst[j] -> sA[sid], ~240cy) prefetched only ~60cy
// ahead. R9 kF: per 64-stroke block each lane gathers ONE stroke into
// registers, inner loop broadcasts via v_readlane (8/stroke, no memory).
// Pipeline: kA loses the 4096-bin histogram (2M device atomics); kD's 4
// blocks/supercell each hist the supercell's u8 keys per-quarter ->
// identical deterministic cell bases, no cellCur atomics, no big kScan.
// sortedTmp aliases out[0..4n) (dead until kF writes density/rgb).

#define NC_DIM 16
#define NC (NC_DIM * NC_DIM * NC_DIM)   // 4096 cells = 64 supercells x 64 sub
#define MAXS 512
#define CELL_INV 8.0f
#define CHK 128                          // points per chunk (2 per lane)

typedef unsigned char u8;
typedef unsigned short u16;
typedef unsigned long long u64;

__device__ __forceinline__ void contract_pt(float x, float y, float z,
                                            float& cx, float& cy, float& cz) {
    float n2 = fmaf(x, x, fmaf(y, y, z * z));
    float nn = fmaxf(__builtin_amdgcn_sqrtf(n2), 1e-9f);
    float invn = 1.0f / nn;
    float scl = (nn <= 1.0f) ? 0.5f : (2.0f - invn) * (0.5f * invn);
    cx = x * scl; cy = y * scl; cz = z * scl;
}

__device__ __forceinline__ int cid_of(float cx, float cy, float cz) {
    int ix = (int)floorf((cx + 1.0f) * CELL_INV);
    int iy = (int)floorf((cy + 1.0f) * CELL_INV);
    int iz = (int)floorf((cz + 1.0f) * CELL_INV);
    ix = min(max(ix, 0), 15); iy = min(max(iy, 0), 15); iz = min(max(iz, 0), 15);
    return ix | (iy << 4) | (iz << 8);
}
__device__ __forceinline__ int sid_of(int cid) {   // supercell 0..63
    return ((cid >> 2) & 3) | (((cid >> 6) & 3) << 2) | (((cid >> 10) & 3) << 4);
}
__device__ __forceinline__ int sub_of(int cid) {   // subcell 0..63
    return (cid & 3) | (((cid >> 4) & 3) << 2) | (((cid >> 8) & 3) << 4);
}
__device__ __forceinline__ int cid_from(int s, int t) {
    int ix = (((s) & 3) << 2) | (t & 3);
    int iy = (((s >> 2) & 3) << 2) | ((t >> 2) & 3);
    int iz = (((s >> 4) & 3) << 2) | ((t >> 4) & 3);
    return ix | (iy << 4) | (iz << 8);
}
__device__ __forceinline__ float bcast(float v, int l) {
    return __int_as_float(__builtin_amdgcn_readlane(__float_as_int(v), l));
}

// KA: contract, write cw, supercell histogram (LDS-agg, 8-way replicated).
__global__ __launch_bounds__(256) void kA(
    const float* __restrict__ coords, float* __restrict__ out,
    int* __restrict__ superCntR, int n)
{
    __shared__ int h[64];
    if (threadIdx.x < 64) h[threadIdx.x] = 0;
    __syncthreads();
    float* cw = out + 4 * (size_t)n;
    int base = blockIdx.x * 2048 + threadIdx.x;
#pragma unroll
    for (int k = 0; k < 8; ++k) {
        int i = base + k * 256;
        if (i < n) {
            float cx, cy, cz;
            contract_pt(coords[3 * i], coords[3 * i + 1], coords[3 * i + 2], cx, cy, cz);
            cw[3 * i] = cx; cw[3 * i + 1] = cy; cw[3 * i + 2] = cz;
            atomicAdd(&h[sid_of(cid_of(cx, cy, cz))], 1);
        }
    }
    __syncthreads();
    if (threadIdx.x < 64 && h[threadIdx.x])
        atomicAdd(&superCntR[(blockIdx.x & 7) * 64 + threadIdx.x], h[threadIdx.x]);
}

// KB: reduce replicas + three 64-wide shuffle scans (element, padded slot,
// padded chunk capacities).
__global__ __launch_bounds__(64) void kB(
    const int* __restrict__ superCntR, int* __restrict__ superCnt,
    int* __restrict__ superBase, int* __restrict__ superCur,
    int* __restrict__ superSlotBase, int* __restrict__ superChunkBase)
{
    int t = threadIdx.x;
    int cnt = 0;
#pragma unroll
    for (int r = 0; r < 8; ++r) cnt += superCntR[r * 64 + t];
    int e = cnt;
    int sc = cnt + 64 * CHK;                 // per-cell round-up pad bound
    int ch = ((cnt + CHK - 1) >> 7) + 65;
    int ve = e, vs = sc, vc = ch;
    for (int off = 1; off < 64; off <<= 1) {
        int ue = __shfl_up(ve, off, 64);
        int us = __shfl_up(vs, off, 64);
        int uc = __shfl_up(vc, off, 64);
        if (t >= off) { ve += ue; vs += us; vc += uc; }
    }
    superCnt[t] = cnt;
    superBase[t] = ve - e;
    superCur[t] = ve - e;
    superSlotBase[t] = vs - sc;
    superChunkBase[t] = vc - ch;
}

// KC: block-aggregated scatter of float4(cw, idx|sub<<21) + u8 sub-key
// into supercell element runs. sortedTmp aliases out[0..4n).
__global__ __launch_bounds__(256) void kC(
    const float* __restrict__ out, int* __restrict__ superCur,
    float4* __restrict__ sortedTmp, u8* __restrict__ keyArr, int n)
{
    __shared__ int scnt[64], sbase[64];
    if (threadIdx.x < 64) scnt[threadIdx.x] = 0;
    __syncthreads();
    const float* cw = out + 4 * (size_t)n;
    int base = blockIdx.x * 2048 + threadIdx.x;
    float cx[8], cy[8], cz[8];
    int sub[8], sid[8];
#pragma unroll
    for (int k = 0; k < 8; ++k) {
        int i = base + k * 256;
        if (i < n) {
            cx[k] = cw[3 * i]; cy[k] = cw[3 * i + 1]; cz[k] = cw[3 * i + 2];
            int c = cid_of(cx[k], cy[k], cz[k]);
            sub[k] = sub_of(c); sid[k] = sid_of(c);
            atomicAdd(&scnt[sid[k]], 1);
        } else sid[k] = -1;
    }
    __syncthreads();
    if (threadIdx.x < 64) {
        int c = scnt[threadIdx.x];
        sbase[threadIdx.x] = c ? atomicAdd(&superCur[threadIdx.x], c) : 0;
        scnt[threadIdx.x] = 0;
    }
    __syncthreads();
#pragma unroll
    for (int k = 0; k < 8; ++k) {
        if (sid[k] >= 0) {
            int i = base + k * 256;
            int r = atomicAdd(&scnt[sid[k]], 1);
            int slot = sbase[sid[k]] + r;
            sortedTmp[slot] = make_float4(cx[k], cy[k], cz[k],
                                          __int_as_float(i | (sub[k] << 21)));
            keyArr[slot] = (u8)sub[k];
        }
    }
}

// KD: 4 blocks per supercell (blockIdx = g*64+s -> same XCD per supercell).
// Each block: per-quarter 64-bin hist from u8 keys -> identical deterministic
// cell slot bases (no global atomics); g==0 emits chunkInfo; scatter own
// quarter into 128-aligned cell chunks.
__global__ __launch_bounds__(1024) void kD(
    const int* __restrict__ superCnt, const int* __restrict__ superBase,
    const int* __restrict__ superSlotBase, const int* __restrict__ superChunkBase,
    const float4* __restrict__ sortedTmp, const u8* __restrict__ keyArr,
    float4* __restrict__ sortedPts, int2* __restrict__ chunkInfo)
{
    __shared__ int hist[4][64];
    __shared__ int cur[64];
    int s = blockIdx.x & 63, g = blockIdx.x >> 6;
    int t = threadIdx.x;
    if (t < 256) ((int*)hist)[t] = 0;
    __syncthreads();
    int cnt = superCnt[s];
    int rb = superBase[s];
    int qb1 = (int)(((long long)cnt * 1) >> 2);
    int qb2 = (int)(((long long)cnt * 2) >> 2);
    int qb3 = (int)(((long long)cnt * 3) >> 2);
    for (int j = t; j < cnt; j += 1024) {
        int sub = keyArr[rb + j];
        int qr = (j >= qb2) ? ((j >= qb3) ? 3 : 2) : ((j >= qb1) ? 1 : 0);
        atomicAdd(&hist[qr][sub], 1);
    }
    __syncthreads();
    if (t < 64) {
        int c = hist[0][t] + hist[1][t] + hist[2][t] + hist[3][t];
        int slotsz = ((c + CHK - 1) >> 7) << 7;
        int nch = (c + CHK - 1) >> 7;
        int vs = slotsz, vc = nch;
        for (int off = 1; off < 64; off <<= 1) {
            int us = __shfl_up(vs, off, 64);
            int uc = __shfl_up(vc, off, 64);
            if (t >= off) { vs += us; vc += uc; }
        }
        int cellSlot = superSlotBase[s] + (vs - slotsz);
        if (g == 0) {
            int cb = superChunkBase[s] + (vc - nch);
            int cid = cid_from(s, t);
            for (int q = 0; q < nch; ++q) {
                int rem = c - (q << 7); rem = rem > CHK ? CHK : rem;
                chunkInfo[cb + q] = make_int2(cid | (rem << 16), cellSlot + (q << 7));
            }
        }
        int pre = 0;
        for (int gg = 0; gg < g; ++gg) pre += hist[gg][t];
        cur[t] = cellSlot + pre;
    }
    __syncthreads();
    int q0 = (g == 0) ? 0 : ((g == 1) ? qb1 : ((g == 2) ? qb2 : qb3));
    int q1 = (g == 0) ? qb1 : ((g == 1) ? qb2 : ((g == 2) ? qb3 : cnt));
    for (int j = q0 + t; j < q1; j += 1024) {
        float4 p = sortedTmp[rb + j];
        int bits = __float_as_int(p.w);
        int sub = (bits >> 21) & 63;
        int r = atomicAdd(&cur[sub], 1);
        p.w = __int_as_float(bits & 0x1FFFFF);
        sortedPts[r] = p;
    }
}

// KF: one wave per 128-pt chunk (2 pts/lane). On-the-fly stroke list, then
// register-broadcast blend: per 64-stroke block each lane gathers ONE
// stroke into regs; inner loop uses v_readlane only (no memory ops).
__global__ __launch_bounds__(256) void kF(
    const float* __restrict__ shape, const float* __restrict__ color,
    const float* __restrict__ alpha,
    const int2* __restrict__ chunkInfo, const float4* __restrict__ sortedPts,
    float* __restrict__ out, int n, int ns, int maxChunks)
{
    __shared__ float4 sA[MAXS];      // (ax, ay, az, K = 0.5 - 5r)
    __shared__ float4 sB[MAXS];      // (dp, cr, cg, cb)
    __shared__ u16 wl[4][MAXS];      // per-wave stroke sublist
    for (int s = threadIdx.x; s < ns; s += blockDim.x) {
        float4 sp = ((const float4*)shape)[s];
        sA[s] = make_float4(sp.x, sp.y, sp.z, fmaf(-5.0f, sp.w, 0.5f));
        sB[s] = make_float4(fmaxf(alpha[s], 0.0f) * 50.0f,
                            color[3 * s], color[3 * s + 1], color[3 * s + 2]);
    }
    __syncthreads();

    int w = threadIdx.x >> 6, lane = threadIdx.x & 63;
    int k = blockIdx.x * 4 + w;
    if (k >= maxChunks) return;
    int2 info = chunkInfo[k];
    if (info.x < 0) return;
    int cell = info.x & 0xFFF;
    int cnum = info.x >> 16;          // 1..128

    float4 pA = sortedPts[info.y + lane];
    float4 pB = sortedPts[info.y + 64 + lane];
    bool vA = lane < cnum;
    bool vB = lane + 64 < cnum;
    int iA = __float_as_int(pA.w) & 0x1FFFFF;
    int iB = __float_as_int(pB.w) & 0x1FFFFF;
    float xA = vA ? pA.x : 1e9f, yA = vA ? pA.y : 1e9f, zA = vA ? pA.z : 1e9f;
    float xB = vB ? pB.x : 1e9f, yB = vB ? pB.y : 1e9f, zB = vB ? pB.z : 1e9f;

    // Build this cell's ordered stroke sublist (AABB vs sphere, from sA).
    int ix = cell & 15, iy = (cell >> 4) & 15, iz = cell >> 8;
    float lox = -1.0f + ix * 0.125f, hix = lox + 0.125f;
    float loy = -1.0f + iy * 0.125f, hiy = loy + 0.125f;
    float loz = -1.0f + iz * 0.125f, hiz = loz + 0.125f;
    u16* lst = wl[w];
    int nl = 0;
    for (int bs = 0; bs < ns; bs += 64) {
        int s = bs + lane;
        bool pass = false;
        if (s < ns) {
            float4 a = sA[s];
            float dx = a.x - fminf(fmaxf(a.x, lox), hix);
            float dy = a.y - fminf(fmaxf(a.y, loy), hiy);
            float dz = a.z - fminf(fmaxf(a.z, loz), hiz);
            float d2 = fmaf(dx, dx, fmaf(dy, dy, dz * dz));
            float rr = fmaf(-0.2f, a.w, 0.201f);   // r + 0.101
            pass = d2 <= rr * rr;
        }
        u64 m = __ballot(pass);
        if (pass) lst[nl + __popcll(m & ((1ull << lane) - 1ull))] = (u16)s;
        nl += __popcll(m);
    }

    float TA = 1.0f, dA = 0.0f, rA = 0.0f, gA = 0.0f, bA = 0.0f;
    float TB = 1.0f, dB = 0.0f, rB = 0.0f, gB = 0.0f, bB = 0.0f;
    if (nl > 0) {
        int jb = ((((nl + 63) >> 6) << 6)) - 64;
        int id = lst[min(jb + lane, nl - 1)];
        float4 mA = sA[id], mB = sB[id];
        for (; jb >= 0; jb -= 64) {
            // prefetch next (lower) block's per-lane stroke
            float4 nA = mA, nB = mB;
            int jbn = jb - 64;
            if (jbn >= 0) {
                int idn = lst[jbn + lane];
                nA = sA[idn]; nB = sB[idn];
            }
            int hi = nl - jb; hi = hi > 64 ? 64 : hi;
            for (int jj = hi - 1; jj >= 0; --jj) {
                float ax = bcast(mA.x, jj), ay = bcast(mA.y, jj);
                float az = bcast(mA.z, jj), aw = bcast(mA.w, jj);
                float bx = bcast(mB.x, jj), by = bcast(mB.y, jj);
                float bz = bcast(mB.z, jj), bw = bcast(mB.w, jj);
                // point A
                float dxA = xA - ax, dyA = yA - ay, dzA = zA - az;
                float d2A = fmaf(dxA, dxA, fmaf(dyA, dyA, dzA * dzA));
                float omtA = fminf(fmaxf(fmaf(5.0f, __builtin_amdgcn_sqrtf(d2A), aw), 0.0f), 1.0f);
                float TnA = omtA * TA;
                float tTA = TA - TnA;
                dA = fmaf(tTA, bx, dA); rA = fmaf(tTA, by, rA);
                gA = fmaf(tTA, bz, gA); bA = fmaf(tTA, bw, bA);
                TA = TnA;
                // point B
                float dxB = xB - ax, dyB = yB - ay, dzB = zB - az;
                float d2B = fmaf(dxB, dxB, fmaf(dyB, dyB, dzB * dzB));
                float omtB = fminf(fmaxf(fmaf(5.0f, __builtin_amdgcn_sqrtf(d2B), aw), 0.0f), 1.0f);
                float TnB = omtB * TB;
                float tTB = TB - TnB;
                dB = fmaf(tTB, bx, dB); rB = fmaf(tTB, by, rB);
                gB = fmaf(tTB, bz, gB); bB = fmaf(tTB, bw, bB);
                TB = TnB;
            }
            mA = nA; mB = nB;
        }
    }

    float* rgb = out + n;
    if (vA) {
        float inv = 1.0f / (1.0f + 1e-6f - TA);
        out[iA] = dA;
        rgb[3 * iA]     = fminf(fmaxf(rA * inv, 0.0f), 1.0f);
        rgb[3 * iA + 1] = fminf(fmaxf(gA * inv, 0.0f), 1.0f);
        rgb[3 * iA + 2] = fminf(fmaxf(bA * inv, 0.0f), 1.0f);
    }
    if (vB) {
        float inv = 1.0f / (1.0f + 1e-6f - TB);
        out[iB] = dB;
        rgb[3 * iB]     = fminf(fmaxf(rB * inv, 0.0f), 1.0f);
        rgb[3 * iB + 1] = fminf(fmaxf(gB * inv, 0.0f), 1.0f);
        rgb[3 * iB + 2] = fminf(fmaxf(bB * inv, 0.0f), 1.0f);
    }
}

// ---- Fallback: R4 direct kernel ----
#define PTS 4
__global__ __launch_bounds__(256) void stroke_direct(
    const float* __restrict__ coords, const float* __restrict__ shape,
    const float* __restrict__ color, const float* __restrict__ alpha,
    float* __restrict__ out, int n, int ns)
{
    __shared__ float4 fA[MAXS + 1];
    __shared__ float4 fB[MAXS + 1];
    for (int s = threadIdx.x; s < ns; s += blockDim.x) {
        float4 sp = ((const float4*)shape)[s];
        fA[s + 1] = make_float4(sp.x, sp.y, sp.z, fmaf(-5.0f, sp.w, 0.5f));
        fB[s + 1] = make_float4(fmaxf(alpha[s], 0.0f) * 50.0f,
                                color[3 * s], color[3 * s + 1], color[3 * s + 2]);
    }
    __syncthreads();
    const int base = blockIdx.x * (blockDim.x * PTS) + threadIdx.x;
    float cx[PTS], cy[PTS], cz[PTS], T[PTS], Ad[PTS], Ar[PTS], Ag[PTS], Ab[PTS];
#pragma unroll
    for (int k = 0; k < PTS; ++k) {
        int i = base + k * 256; i = (i < n) ? i : (n - 1);
        contract_pt(coords[3 * i], coords[3 * i + 1], coords[3 * i + 2],
                    cx[k], cy[k], cz[k]);
        T[k] = 1.0f; Ad[k] = Ar[k] = Ag[k] = Ab[k] = 0.0f;
    }
    float4 a = fA[ns], b = fB[ns];
#pragma unroll 2
    for (int s = ns - 1; s >= 0; --s) {
        float4 an = fA[s], bn = fB[s];
#pragma unroll
        for (int k = 0; k < PTS; ++k) {
            float dx = cx[k] - a.x, dy = cy[k] - a.y, dz = cz[k] - a.z;
            float d2 = fmaf(dx, dx, fmaf(dy, dy, dz * dz));
            float dist = __builtin_amdgcn_sqrtf(d2);
            float omt = fminf(fmaxf(fmaf(5.0f, dist, a.w), 0.0f), 1.0f);
            float Tn = omt * T[k];
            float tT = T[k] - Tn;
            Ad[k] = fmaf(tT, b.x, Ad[k]); Ar[k] = fmaf(tT, b.y, Ar[k]);
            Ag[k] = fmaf(tT, b.z, Ag[k]); Ab[k] = fmaf(tT, b.w, Ab[k]);
            T[k] = Tn;
        }
        a = an; b = bn;
    }
    float* rgb = out + n;
    float* cw  = out + 4 * (size_t)n;
#pragma unroll
    for (int k = 0; k < PTS; ++k) {
        int i = base + k * 256;
        if (i >= n) break;
        float inv = 1.0f / (1.0f + 1e-6f - T[k]);
        out[i] = Ad[k];
        rgb[3 * i]     = fminf(fmaxf(Ar[k] * inv, 0.0f), 1.0f);
        rgb[3 * i + 1] = fminf(fmaxf(Ag[k] * inv, 0.0f), 1.0f);
        rgb[3 * i + 2] = fminf(fmaxf(Ab[k] * inv, 0.0f), 1.0f);
        cw[3 * i]     = cx[k];
        cw[3 * i + 1] = cy[k];
        cw[3 * i + 2] = cz[k];
    }
}

extern "C" void kernel_launch(void* const* d_in, const int* in_sizes, int n_in,
                              void* d_out, int out_size, void* d_ws, size_t ws_size,
                              hipStream_t stream) {
    const float* coords = (const float*)d_in[0];
    const float* shape  = (const float*)d_in[1];
    const float* color  = (const float*)d_in[2];
    const float* alpha  = (const float*)d_in[3];
    float* out = (float*)d_out;

    int n  = in_sizes[0] / 3;
    int ns = in_sizes[1] / 4;

    auto al = [](size_t v) { return (v + 255) & ~(size_t)255; };

    int maxChunks = (n + CHK - 1) / CHK + 64 * 65;
    size_t slotCap = (size_t)n + 64 * 64 * CHK;   // per-supercell padded slots

    size_t o_superCntR  = 0;                       // 8*64*4 = 2048
    size_t o_superCnt   = 2048;                    // 256
    size_t o_superBase  = 2304;                    // 256
    size_t o_superCur   = 2560;                    // 256
    size_t o_superSlotB = 2816;                    // 256
    size_t o_superChB   = 3072;                    // 256
    size_t o_chunk      = al(3328);
    size_t o_key        = al(o_chunk + (size_t)maxChunks * 8);
    size_t o_pts        = al(o_key + (size_t)n);
    size_t need         = o_pts + slotCap * 16;

    if (ws_size >= need && ns <= MAXS && n >= 1 && n <= (1 << 21)) {
        char* w = (char*)d_ws;
        int*    superCntR = (int*)(w + o_superCntR);
        int*    superCnt  = (int*)(w + o_superCnt);
        int*    superBase = (int*)(w + o_superBase);
        int*    superCur  = (int*)(w + o_superCur);
        int*    superSlotB= (int*)(w + o_superSlotB);
        int*    superChB  = (int*)(w + o_superChB);
        int2*   chunkInfo = (int2*)(w + o_chunk);
        u8*     keyArr    = (u8*)(w + o_key);
        float4* sortedPts = (float4*)(w + o_pts);
        float4* sortedTmp = (float4*)out;          // aliases density+rgb region

        hipMemsetAsync(superCntR, 0, 2048, stream);
        hipMemsetAsync(chunkInfo, 0xFF, (size_t)maxChunks * 8, stream);

        kA<<<(n + 2047) / 2048, 256, 0, stream>>>(coords, out, superCntR, n);
        kB<<<1, 64, 0, stream>>>(superCntR, superCnt, superBase, superCur,
                                 superSlotB, superChB);
        kC<<<(n + 2047) / 2048, 256, 0, stream>>>(out, superCur, sortedTmp,
                                                  keyArr, n);
        kD<<<256, 1024, 0, stream>>>(superCnt, superBase, superSlotB, superChB,
                                     sortedTmp, keyArr, sortedPts, chunkInfo);
        kF<<<(maxChunks + 3) / 4, 256, 0, stream>>>(
            shape, color, alpha, chunkInfo, sortedPts, out, n, ns, maxChunks);
    } else {
        int per_block = 256 * PTS;
        int grid = (n + per_block - 1) / per_block;
        stroke_direct<<<grid, 256, 0, stream>>>(coords, shape, color, alpha, out, n, ns);
    }
}